// Round 1
// baseline (5603.902 us; speedup 1.0000x reference)
//
#include <hip/hip_runtime.h>
#include <hip/hip_bf16.h>

// Problem constants (from reference)
#define NN 100000
#define EE 1600000
#define FF 128
#define HH 128
#define AA 8

// ---------------- degree / norm ----------------
__global__ void k_deg_init(float* deg, int n) {
    int i = blockIdx.x * blockDim.x + threadIdx.x;
    if (i < n) deg[i] = 1.0f;  // self-loop
}

__global__ void k_deg_count(const int* __restrict__ ei, float* __restrict__ deg, int e) {
    int i = blockIdx.x * blockDim.x + threadIdx.x;
    if (i < e) atomicAdd(&deg[ei[e + i]], 1.0f);  // dst row is ei[E..2E)
}

__global__ void k_rsqrt(float* d, int n) {
    int i = blockIdx.x * blockDim.x + threadIdx.x;
    if (i < n) d[i] = rsqrtf(d[i]);
}

// ---------------- GEMM: out[i][j] = dis[i] * sum_k A[i][k] W[k][j] ----------------
// A: [n,128], W: [128,128], out: [n,128]
#define BM 64
#define BK 32

__launch_bounds__(256, 2)
__global__ void k_gemm_scale(const float* __restrict__ A,
                             const float* __restrict__ W,
                             const float* __restrict__ dis,
                             float* __restrict__ out, int n)
{
    __shared__ float sA[BK][BM + 4];   // transposed: sA[k][row], stride 68 keeps 16B align
    __shared__ float sB[BK][128];
    const int tid = threadIdx.x;
    const int row0 = blockIdx.x * BM;
    const int tr = tid >> 4;   // 0..15 -> rows tr*4..tr*4+3
    const int tc = tid & 15;   // 0..15 -> cols tc*4..+3 and 64+tc*4..+3

    float acc[4][8];
#pragma unroll
    for (int r = 0; r < 4; r++)
#pragma unroll
        for (int c = 0; c < 8; c++) acc[r][c] = 0.f;

    for (int k0 = 0; k0 < 128; k0 += BK) {
        __syncthreads();
        // stage A tile (64 rows x 32 k), transposed into sA
#pragma unroll
        for (int i = 0; i < 2; i++) {
            int f = tid + i * 256;       // 0..511 float4 id
            int row = f >> 3;            // 0..63
            int kq = f & 7;              // 0..7
            int gr = row0 + row; if (gr >= n) gr = n - 1;
            float4 v = *(const float4*)&A[(long long)gr * 128 + k0 + kq * 4];
            sA[kq * 4 + 0][row] = v.x;
            sA[kq * 4 + 1][row] = v.y;
            sA[kq * 4 + 2][row] = v.z;
            sA[kq * 4 + 3][row] = v.w;
        }
        // stage B tile (32 k x 128 cols)
#pragma unroll
        for (int i = 0; i < 4; i++) {
            int f = tid + i * 256;       // 0..1023 float4 id
            int kk = f >> 5;             // 0..31
            int cq = f & 31;             // 0..31
            *(float4*)&sB[kk][cq * 4] = *(const float4*)&W[(k0 + kk) * 128 + cq * 4];
        }
        __syncthreads();
#pragma unroll
        for (int kk = 0; kk < BK; kk++) {
            float4 a4 = *(const float4*)&sA[kk][tr * 4];
            float4 bl = *(const float4*)&sB[kk][tc * 4];
            float4 bh = *(const float4*)&sB[kk][64 + tc * 4];
            float a_[4] = {a4.x, a4.y, a4.z, a4.w};
            float b_[8] = {bl.x, bl.y, bl.z, bl.w, bh.x, bh.y, bh.z, bh.w};
#pragma unroll
            for (int r = 0; r < 4; r++)
#pragma unroll
                for (int c = 0; c < 8; c++)
                    acc[r][c] += a_[r] * b_[c];
        }
    }
#pragma unroll
    for (int r = 0; r < 4; r++) {
        int gr = row0 + tr * 4 + r;
        if (gr < n) {
            float d = dis[gr];
            float4 lo = make_float4(acc[r][0] * d, acc[r][1] * d, acc[r][2] * d, acc[r][3] * d);
            float4 hi = make_float4(acc[r][4] * d, acc[r][5] * d, acc[r][6] * d, acc[r][7] * d);
            *(float4*)&out[(long long)gr * 128 + tc * 4] = lo;
            *(float4*)&out[(long long)gr * 128 + 64 + tc * 4] = hi;
        }
    }
}

// ---------------- edge scatter: agg[dst] += hw[src] ----------------
// one thread per (edge, 4-feature chunk); 32 threads per edge
__global__ void k_scatter(const int* __restrict__ ei,
                          const float* __restrict__ hw,
                          float* __restrict__ agg, int e)
{
    int t = blockIdx.x * blockDim.x + threadIdx.x;
    int edge = t >> 5;
    if (edge >= e) return;
    int c = (t & 31) * 4;
    int src = ei[edge];
    int dst = ei[e + edge];
    float4 v = *(const float4*)&hw[src * 128 + c];
    float* p = &agg[dst * 128 + c];
    atomicAdd(p + 0, v.x);
    atomicAdd(p + 1, v.y);
    atomicAdd(p + 2, v.z);
    atomicAdd(p + 3, v.w);
}

// ---------------- combine: h = relu(dis[i]*(agg[i] + hw[i]) + b) ----------------
__global__ void k_combine(const float* __restrict__ agg,
                          const float* __restrict__ hw,
                          const float* __restrict__ dis,
                          const float* __restrict__ b,
                          float* __restrict__ h, int n)
{
    int t = blockIdx.x * blockDim.x + threadIdx.x;
    int i = t >> 5;
    if (i >= n) return;
    int c = (t & 31) * 4;
    float d = dis[i];
    float4 a = *(const float4*)&agg[i * 128 + c];
    float4 s = *(const float4*)&hw[i * 128 + c];
    float4 bb = *(const float4*)&b[c];
    float4 o;
    o.x = fmaxf(d * (a.x + s.x) + bb.x, 0.f);
    o.y = fmaxf(d * (a.y + s.y) + bb.y, 0.f);
    o.z = fmaxf(d * (a.z + s.z) + bb.z, 0.f);
    o.w = fmaxf(d * (a.w + s.w) + bb.w, 0.f);
    *(float4*)&h[i * 128 + c] = o;
}

// ---------------- FC head: out[i][a] = sum_k h[i][k] Wfc[k][a] + bfc[a] ----------------
__launch_bounds__(256)
__global__ void k_fc(const float* __restrict__ h,
                     const float* __restrict__ Wfc,
                     const float* __restrict__ bfc,
                     float* __restrict__ out, int n)
{
    __shared__ float sW[128 * 8];
    __shared__ float sH[32][132];
    const int tid = threadIdx.x;
    // Wfc: 1024 floats, 1 float4/thread
    *(float4*)&sW[tid * 4] = *(const float4*)&Wfc[tid * 4];
    const int n0 = blockIdx.x * 32;
#pragma unroll
    for (int i = 0; i < 4; i++) {
        int f = tid + i * 256;   // float4 id in [0,1024)
        int node = f >> 5;       // 0..31
        int kq = f & 31;         // 0..31
        int gn = n0 + node; if (gn >= n) gn = n - 1;
        *(float4*)&sH[node][kq * 4] = *(const float4*)&h[(long long)gn * 128 + kq * 4];
    }
    __syncthreads();
    const int node = tid >> 3;
    const int a = tid & 7;
    float acc = bfc[a];
#pragma unroll
    for (int k = 0; k < 128; k++)
        acc += sH[node][k] * sW[k * 8 + a];
    int gn = n0 + node;
    if (gn < n) out[gn * 8 + a] = acc;
}

extern "C" void kernel_launch(void* const* d_in, const int* in_sizes, int n_in,
                              void* d_out, int out_size, void* d_ws, size_t ws_size,
                              hipStream_t stream) {
    const float* x   = (const float*)d_in[0];
    const int*   ei  = (const int*)d_in[1];   // [2,E] int32: src=[0,E), dst=[E,2E)
    const float* W1  = (const float*)d_in[2];
    const float* b1  = (const float*)d_in[3];
    const float* W2  = (const float*)d_in[4];
    const float* b2  = (const float*)d_in[5];
    const float* Wfc = (const float*)d_in[6];
    const float* bfc = (const float*)d_in[7];
    float* out = (float*)d_out;

    const int n = NN, e = EE;

    // workspace layout
    char* ws = (char*)d_ws;
    float* dis  = (float*)(ws);                       // N floats
    float* bufA = (float*)(ws + (1 << 19));           // N*128 floats (51.2 MB)
    float* bufB = (float*)(ws + (1 << 19) + (size_t)NN * 128 * 4);
    const size_t HBYTES = (size_t)NN * 128 * 4;

    // 1. degree + rsqrt
    k_deg_init<<<(n + 255) / 256, 256, 0, stream>>>(dis, n);
    k_deg_count<<<(e + 255) / 256, 256, 0, stream>>>(ei, dis, e);
    k_rsqrt<<<(n + 255) / 256, 256, 0, stream>>>(dis, n);

    const int gemm_grid = (n + BM - 1) / BM;
    const int scat_grid = (e * 32 + 255) / 256;
    const int comb_grid = (n * 32 + 255) / 256;

    // 2. layer 1: hw1' = (x @ W1) * dis  -> bufA
    k_gemm_scale<<<gemm_grid, 256, 0, stream>>>(x, W1, dis, bufA, n);
    // 3. aggregate: bufB = sum_{src->dst} bufA[src]
    hipMemsetAsync(bufB, 0, HBYTES, stream);
    k_scatter<<<scat_grid, 256, 0, stream>>>(ei, bufA, bufB, e);
    // 4. h1 = relu(dis*(agg + self) + b1) -> bufA (in-place elementwise ok)
    k_combine<<<comb_grid, 256, 0, stream>>>(bufB, bufA, dis, b1, bufA, n);

    // 5. layer 2: hw2' = (h1 @ W2) * dis -> bufB
    k_gemm_scale<<<gemm_grid, 256, 0, stream>>>(bufA, W2, dis, bufB, n);
    // 6. aggregate -> bufA
    hipMemsetAsync(bufA, 0, HBYTES, stream);
    k_scatter<<<scat_grid, 256, 0, stream>>>(ei, bufB, bufA, e);
    // 7. h2 = relu(dis*(agg + self) + b2) -> bufB
    k_combine<<<comb_grid, 256, 0, stream>>>(bufA, bufB, dis, b2, bufB, n);

    // 8. FC head
    k_fc<<<(n + 31) / 32, 256, 0, stream>>>(bufB, Wfc, bfc, out, n);
}

// Round 2
// 722.261 us; speedup vs baseline: 7.7588x; 7.7588x over previous
//
#include <hip/hip_runtime.h>
#include <hip/hip_bf16.h>

#define NN 100000
#define EE 1600000
#define FF 128
#define HH 128
#define AA 8

// ---------------- small utility kernels ----------------
__global__ void k_zero_int(int* p, int n) {
    int i = blockIdx.x * blockDim.x + threadIdx.x;
    if (i < n) p[i] = 0;
}

__global__ void k_count(const int* __restrict__ ei, int* __restrict__ cnt, int e) {
    int i = blockIdx.x * blockDim.x + threadIdx.x;
    if (i < e) atomicAdd(&cnt[ei[e + i]], 1);   // dst rows live at ei[E..2E)
}

__global__ void k_dis(const int* __restrict__ cnt, float* __restrict__ dis, int n) {
    int i = blockIdx.x * blockDim.x + threadIdx.x;
    if (i < n) dis[i] = rsqrtf((float)cnt[i] + 1.0f);  // +1 self-loop
}

// single-block exclusive scan over n (<= 1024*CH) elements
__global__ __launch_bounds__(1024)
void k_scan(const int* __restrict__ cnt, int* __restrict__ row_start, int n) {
    __shared__ int s[1024];
    const int t = threadIdx.x;
    const int CH = (n + 1023) / 1024;
    const int base = t * CH;
    int sum = 0;
    for (int i = 0; i < CH; i++) {
        int idx = base + i;
        if (idx < n) sum += cnt[idx];
    }
    s[t] = sum;
    __syncthreads();
    for (int off = 1; off < 1024; off <<= 1) {
        int v = (t >= off) ? s[t - off] : 0;
        __syncthreads();
        s[t] += v;
        __syncthreads();
    }
    int run = (t == 0) ? 0 : s[t - 1];
    for (int i = 0; i < CH; i++) {
        int idx = base + i;
        if (idx < n) { row_start[idx] = run; run += cnt[idx]; }
    }
}

// bucket fill: csr_src[row_start[dst] + k] = src
__global__ void k_fill(const int* __restrict__ ei,
                       const int* __restrict__ row_start,
                       int* __restrict__ cur,
                       int* __restrict__ csr_src, int e) {
    int i = blockIdx.x * blockDim.x + threadIdx.x;
    if (i >= e) return;
    int src = ei[i];
    int dst = ei[e + i];
    int pos = row_start[dst] + atomicAdd(&cur[dst], 1);
    csr_src[pos] = src;
}

// ---------------- GEMM: out[i][j] = dis[i] * sum_k A[i][k] W[k][j] ----------------
#define BM 64
#define BK 32

__launch_bounds__(256, 2)
__global__ void k_gemm_scale(const float* __restrict__ A,
                             const float* __restrict__ W,
                             const float* __restrict__ dis,
                             float* __restrict__ out, int n)
{
    __shared__ float sA[BK][BM + 4];
    __shared__ float sB[BK][128];
    const int tid = threadIdx.x;
    const int row0 = blockIdx.x * BM;
    const int tr = tid >> 4;
    const int tc = tid & 15;

    float acc[4][8];
#pragma unroll
    for (int r = 0; r < 4; r++)
#pragma unroll
        for (int c = 0; c < 8; c++) acc[r][c] = 0.f;

    for (int k0 = 0; k0 < 128; k0 += BK) {
        __syncthreads();
#pragma unroll
        for (int i = 0; i < 2; i++) {
            int f = tid + i * 256;
            int row = f >> 3;
            int kq = f & 7;
            int gr = row0 + row; if (gr >= n) gr = n - 1;
            float4 v = *(const float4*)&A[(long long)gr * 128 + k0 + kq * 4];
            sA[kq * 4 + 0][row] = v.x;
            sA[kq * 4 + 1][row] = v.y;
            sA[kq * 4 + 2][row] = v.z;
            sA[kq * 4 + 3][row] = v.w;
        }
#pragma unroll
        for (int i = 0; i < 4; i++) {
            int f = tid + i * 256;
            int kk = f >> 5;
            int cq = f & 31;
            *(float4*)&sB[kk][cq * 4] = *(const float4*)&W[(k0 + kk) * 128 + cq * 4];
        }
        __syncthreads();
#pragma unroll
        for (int kk = 0; kk < BK; kk++) {
            float4 a4 = *(const float4*)&sA[kk][tr * 4];
            float4 bl = *(const float4*)&sB[kk][tc * 4];
            float4 bh = *(const float4*)&sB[kk][64 + tc * 4];
            float a_[4] = {a4.x, a4.y, a4.z, a4.w};
            float b_[8] = {bl.x, bl.y, bl.z, bl.w, bh.x, bh.y, bh.z, bh.w};
#pragma unroll
            for (int r = 0; r < 4; r++)
#pragma unroll
                for (int c = 0; c < 8; c++)
                    acc[r][c] += a_[r] * b_[c];
        }
    }
#pragma unroll
    for (int r = 0; r < 4; r++) {
        int gr = row0 + tr * 4 + r;
        if (gr < n) {
            float d = dis[gr];
            float4 lo = make_float4(acc[r][0] * d, acc[r][1] * d, acc[r][2] * d, acc[r][3] * d);
            float4 hi = make_float4(acc[r][4] * d, acc[r][5] * d, acc[r][6] * d, acc[r][7] * d);
            *(float4*)&out[(long long)gr * 128 + tc * 4] = lo;
            *(float4*)&out[(long long)gr * 128 + 64 + tc * 4] = hi;
        }
    }
}

// ---------------- fused gather-aggregate + self + scale + bias + relu ----------
// one 64-lane wave per dst node; lane owns 2 feature columns (float2)
__launch_bounds__(256)
__global__ void k_agg(const int* __restrict__ csr_src,
                      const int* __restrict__ row_start,
                      const float* __restrict__ hw,     // pre-scaled by dis[row]
                      const float* __restrict__ dis,
                      const float* __restrict__ b,
                      float* __restrict__ out, int n, int e)
{
    int node = blockIdx.x * 4 + (threadIdx.x >> 6);
    if (node >= n) return;
    int lane = threadIdx.x & 63;
    int c = lane * 2;
    int beg = row_start[node];
    int end = (node == n - 1) ? e : row_start[node + 1];

    float2 acc = *(const float2*)&hw[(long long)node * 128 + c];  // self-loop term
    int i = beg;
    // 2-way unrolled for ILP
    for (; i + 1 < end; i += 2) {
        int s0 = csr_src[i];
        int s1 = csr_src[i + 1];
        float2 v0 = *(const float2*)&hw[(long long)s0 * 128 + c];
        float2 v1 = *(const float2*)&hw[(long long)s1 * 128 + c];
        acc.x += v0.x + v1.x;
        acc.y += v0.y + v1.y;
    }
    if (i < end) {
        int s0 = csr_src[i];
        float2 v0 = *(const float2*)&hw[(long long)s0 * 128 + c];
        acc.x += v0.x;
        acc.y += v0.y;
    }
    float d = dis[node];
    float2 bb = *(const float2*)&b[c];
    float2 o;
    o.x = fmaxf(fmaf(d, acc.x, bb.x), 0.f);
    o.y = fmaxf(fmaf(d, acc.y, bb.y), 0.f);
    *(float2*)&out[(long long)node * 128 + c] = o;
}

// ---------------- FC head ----------------
__launch_bounds__(256)
__global__ void k_fc(const float* __restrict__ h,
                     const float* __restrict__ Wfc,
                     const float* __restrict__ bfc,
                     float* __restrict__ out, int n)
{
    __shared__ float sW[128 * 8];
    __shared__ float sH[32][132];
    const int tid = threadIdx.x;
    *(float4*)&sW[tid * 4] = *(const float4*)&Wfc[tid * 4];
    const int n0 = blockIdx.x * 32;
#pragma unroll
    for (int i = 0; i < 4; i++) {
        int f = tid + i * 256;
        int node = f >> 5;
        int kq = f & 31;
        int gn = n0 + node; if (gn >= n) gn = n - 1;
        *(float4*)&sH[node][kq * 4] = *(const float4*)&h[(long long)gn * 128 + kq * 4];
    }
    __syncthreads();
    const int node = tid >> 3;
    const int a = tid & 7;
    float acc = bfc[a];
#pragma unroll
    for (int k = 0; k < 128; k++)
        acc += sH[node][k] * sW[k * 8 + a];
    int gn = n0 + node;
    if (gn < n) out[gn * 8 + a] = acc;
}

extern "C" void kernel_launch(void* const* d_in, const int* in_sizes, int n_in,
                              void* d_out, int out_size, void* d_ws, size_t ws_size,
                              hipStream_t stream) {
    const float* x   = (const float*)d_in[0];
    const int*   ei  = (const int*)d_in[1];
    const float* W1  = (const float*)d_in[2];
    const float* b1  = (const float*)d_in[3];
    const float* W2  = (const float*)d_in[4];
    const float* b2  = (const float*)d_in[5];
    const float* Wfc = (const float*)d_in[6];
    const float* bfc = (const float*)d_in[7];
    float* out = (float*)d_out;

    const int n = NN, e = EE;

    // workspace layout
    char* ws = (char*)d_ws;
    float* dis       = (float*)(ws);                        // N f32     (0.4 MB)
    int*   cnt       = (int*)  (ws + (1 << 19));            // N i32
    int*   row_start = (int*)  (ws + 2 * (1 << 19));        // N i32
    int*   cur       = (int*)  (ws + 3 * (1 << 19));        // N i32
    int*   csr_src   = (int*)  (ws + 4 * (1 << 19));        // E i32     (6.4 MB)
    char*  big       = ws + 4 * (1 << 19) + ((size_t)EE * 4 + 4096);
    float* bufA = (float*)(big);                            // N*128 f32 (51.2 MB)
    float* bufB = (float*)(big + (size_t)NN * 128 * 4);

    const int g256n = (n + 255) / 256;
    const int g256e = (e + 255) / 256;

    // ---- CSR build + norms ----
    k_zero_int<<<g256n, 256, 0, stream>>>(cnt, n);
    k_count<<<g256e, 256, 0, stream>>>(ei, cnt, e);
    k_dis<<<g256n, 256, 0, stream>>>(cnt, dis, n);
    k_scan<<<1, 1024, 0, stream>>>(cnt, row_start, n);
    k_zero_int<<<g256n, 256, 0, stream>>>(cur, n);
    k_fill<<<g256e, 256, 0, stream>>>(ei, row_start, cur, csr_src, e);

    const int gemm_grid = (n + BM - 1) / BM;
    const int agg_grid  = (n + 3) / 4;

    // ---- layer 1 ----
    k_gemm_scale<<<gemm_grid, 256, 0, stream>>>(x, W1, dis, bufA, n);
    k_agg<<<agg_grid, 256, 0, stream>>>(csr_src, row_start, bufA, dis, b1, bufB, n, e);

    // ---- layer 2 ----
    k_gemm_scale<<<gemm_grid, 256, 0, stream>>>(bufB, W2, dis, bufA, n);
    k_agg<<<agg_grid, 256, 0, stream>>>(csr_src, row_start, bufA, dis, b2, bufB, n, e);

    // ---- FC head ----
    k_fc<<<(n + 31) / 32, 256, 0, stream>>>(bufB, Wfc, bfc, out, n);
}

// Round 3
// 539.017 us; speedup vs baseline: 10.3965x; 1.3400x over previous
//
#include <hip/hip_runtime.h>
#include <hip/hip_bf16.h>

#define NN 100000
#define EE 1600000
#define FF 128
#define HH 128
#define AA 8

// ---------------- small utility kernels ----------------
__global__ void k_zero_int(int* p, int n) {
    int i = blockIdx.x * blockDim.x + threadIdx.x;
    if (i < n) p[i] = 0;
}

__global__ void k_count(const int* __restrict__ ei, int* __restrict__ cnt, int e) {
    int i = blockIdx.x * blockDim.x + threadIdx.x;
    if (i < e) atomicAdd(&cnt[ei[e + i]], 1);   // dst rows live at ei[E..2E)
}

// ---------------- 3-phase parallel exclusive scan over cnt[n] ----------------
// phase 1: partial[b] = sum of cnt[b*1024 .. b*1024+1023]
__global__ __launch_bounds__(256)
void k_scan_partial(const int* __restrict__ cnt, int* __restrict__ partial, int n) {
    __shared__ int s[256];
    const int t = threadIdx.x;
    const int base = blockIdx.x * 1024 + t * 4;
    int sum = 0;
#pragma unroll
    for (int i = 0; i < 4; i++) {
        int idx = base + i;
        if (idx < n) sum += cnt[idx];
    }
    s[t] = sum;
    __syncthreads();
#pragma unroll
    for (int off = 128; off > 0; off >>= 1) {
        if (t < off) s[t] += s[t + off];
        __syncthreads();
    }
    if (t == 0) partial[blockIdx.x] = s[0];
}

// phase 2: exclusive scan of partial[nb] (nb <= 256), single block
__global__ __launch_bounds__(256)
void k_scan_top(int* __restrict__ partial, int nb) {
    __shared__ int s[256];
    const int t = threadIdx.x;
    s[t] = (t < nb) ? partial[t] : 0;
    __syncthreads();
    for (int off = 1; off < 256; off <<= 1) {
        int v = (t >= off) ? s[t - off] : 0;
        __syncthreads();
        s[t] += v;
        __syncthreads();
    }
    if (t < nb) partial[t] = (t == 0) ? 0 : s[t - 1];
}

// phase 3: per-block exclusive scan + global offset; also emits dis = rsqrt(deg+1)
__global__ __launch_bounds__(256)
void k_scan_final(const int* __restrict__ cnt, const int* __restrict__ partial,
                  int* __restrict__ row_start, float* __restrict__ dis, int n) {
    __shared__ int s[256];
    const int t = threadIdx.x;
    const int base = blockIdx.x * 1024 + t * 4;
    int v[4];
    int sum = 0;
#pragma unroll
    for (int i = 0; i < 4; i++) {
        int idx = base + i;
        v[i] = (idx < n) ? cnt[idx] : 0;
        sum += v[i];
    }
    s[t] = sum;
    __syncthreads();
    for (int off = 1; off < 256; off <<= 1) {
        int x = (t >= off) ? s[t - off] : 0;
        __syncthreads();
        s[t] += x;
        __syncthreads();
    }
    int run = partial[blockIdx.x] + ((t == 0) ? 0 : s[t - 1]);
#pragma unroll
    for (int i = 0; i < 4; i++) {
        int idx = base + i;
        if (idx < n) {
            row_start[idx] = run;
            dis[idx] = rsqrtf((float)v[i] + 1.0f);
            run += v[i];
        }
    }
}

// bucket fill: csr_src[row_start[dst] + k] = src
__global__ void k_fill(const int* __restrict__ ei,
                       const int* __restrict__ row_start,
                       int* __restrict__ cur,
                       int* __restrict__ csr_src, int e) {
    int i = blockIdx.x * blockDim.x + threadIdx.x;
    if (i >= e) return;
    int src = ei[i];
    int dst = ei[e + i];
    int pos = row_start[dst] + atomicAdd(&cur[dst], 1);
    csr_src[pos] = src;
}

// ---------------- GEMM: out[i][j] = dis[i] * sum_k A[i][k] W[k][j] ----------------
#define BM 64
#define BK 32

__launch_bounds__(256, 2)
__global__ void k_gemm_scale(const float* __restrict__ A,
                             const float* __restrict__ W,
                             const float* __restrict__ dis,
                             float* __restrict__ out, int n)
{
    __shared__ float sA[BK][BM + 4];
    __shared__ float sB[BK][128];
    const int tid = threadIdx.x;
    const int row0 = blockIdx.x * BM;
    const int tr = tid >> 4;
    const int tc = tid & 15;

    float acc[4][8];
#pragma unroll
    for (int r = 0; r < 4; r++)
#pragma unroll
        for (int c = 0; c < 8; c++) acc[r][c] = 0.f;

    for (int k0 = 0; k0 < 128; k0 += BK) {
        __syncthreads();
#pragma unroll
        for (int i = 0; i < 2; i++) {
            int f = tid + i * 256;
            int row = f >> 3;
            int kq = f & 7;
            int gr = row0 + row; if (gr >= n) gr = n - 1;
            float4 v = *(const float4*)&A[(long long)gr * 128 + k0 + kq * 4];
            sA[kq * 4 + 0][row] = v.x;
            sA[kq * 4 + 1][row] = v.y;
            sA[kq * 4 + 2][row] = v.z;
            sA[kq * 4 + 3][row] = v.w;
        }
#pragma unroll
        for (int i = 0; i < 4; i++) {
            int f = tid + i * 256;
            int kk = f >> 5;
            int cq = f & 31;
            *(float4*)&sB[kk][cq * 4] = *(const float4*)&W[(k0 + kk) * 128 + cq * 4];
        }
        __syncthreads();
#pragma unroll
        for (int kk = 0; kk < BK; kk++) {
            float4 a4 = *(const float4*)&sA[kk][tr * 4];
            float4 bl = *(const float4*)&sB[kk][tc * 4];
            float4 bh = *(const float4*)&sB[kk][64 + tc * 4];
            float a_[4] = {a4.x, a4.y, a4.z, a4.w};
            float b_[8] = {bl.x, bl.y, bl.z, bl.w, bh.x, bh.y, bh.z, bh.w};
#pragma unroll
            for (int r = 0; r < 4; r++)
#pragma unroll
                for (int c = 0; c < 8; c++)
                    acc[r][c] += a_[r] * b_[c];
        }
    }
#pragma unroll
    for (int r = 0; r < 4; r++) {
        int gr = row0 + tr * 4 + r;
        if (gr < n) {
            float d = dis[gr];
            float4 lo = make_float4(acc[r][0] * d, acc[r][1] * d, acc[r][2] * d, acc[r][3] * d);
            float4 hi = make_float4(acc[r][4] * d, acc[r][5] * d, acc[r][6] * d, acc[r][7] * d);
            *(float4*)&out[(long long)gr * 128 + tc * 4] = lo;
            *(float4*)&out[(long long)gr * 128 + 64 + tc * 4] = hi;
        }
    }
}

// ---------------- fused gather-aggregate + self + scale + bias + relu ----------
// one 64-lane wave per dst node; lane owns 2 feature columns (float2)
__launch_bounds__(256)
__global__ void k_agg(const int* __restrict__ csr_src,
                      const int* __restrict__ row_start,
                      const float* __restrict__ hw,     // pre-scaled by dis[row]
                      const float* __restrict__ dis,
                      const float* __restrict__ b,
                      float* __restrict__ out, int n, int e)
{
    int node = blockIdx.x * 4 + (threadIdx.x >> 6);
    if (node >= n) return;
    int lane = threadIdx.x & 63;
    int c = lane * 2;
    int beg = row_start[node];
    int end = (node == n - 1) ? e : row_start[node + 1];

    float2 acc = *(const float2*)&hw[(long long)node * 128 + c];  // self-loop term
    int i = beg;
    for (; i + 1 < end; i += 2) {
        int s0 = csr_src[i];
        int s1 = csr_src[i + 1];
        float2 v0 = *(const float2*)&hw[(long long)s0 * 128 + c];
        float2 v1 = *(const float2*)&hw[(long long)s1 * 128 + c];
        acc.x += v0.x + v1.x;
        acc.y += v0.y + v1.y;
    }
    if (i < end) {
        int s0 = csr_src[i];
        float2 v0 = *(const float2*)&hw[(long long)s0 * 128 + c];
        acc.x += v0.x;
        acc.y += v0.y;
    }
    float d = dis[node];
    float2 bb = *(const float2*)&b[c];
    float2 o;
    o.x = fmaxf(fmaf(d, acc.x, bb.x), 0.f);
    o.y = fmaxf(fmaf(d, acc.y, bb.y), 0.f);
    *(float2*)&out[(long long)node * 128 + c] = o;
}

// ---------------- FC head ----------------
__launch_bounds__(256)
__global__ void k_fc(const float* __restrict__ h,
                     const float* __restrict__ Wfc,
                     const float* __restrict__ bfc,
                     float* __restrict__ out, int n)
{
    __shared__ float sW[128 * 8];
    __shared__ float sH[32][132];
    const int tid = threadIdx.x;
    *(float4*)&sW[tid * 4] = *(const float4*)&Wfc[tid * 4];
    const int n0 = blockIdx.x * 32;
#pragma unroll
    for (int i = 0; i < 4; i++) {
        int f = tid + i * 256;
        int node = f >> 5;
        int kq = f & 31;
        int gn = n0 + node; if (gn >= n) gn = n - 1;
        *(float4*)&sH[node][kq * 4] = *(const float4*)&h[(long long)gn * 128 + kq * 4];
    }
    __syncthreads();
    const int node = tid >> 3;
    const int a = tid & 7;
    float acc = bfc[a];
#pragma unroll
    for (int k = 0; k < 128; k++)
        acc += sH[node][k] * sW[k * 8 + a];
    int gn = n0 + node;
    if (gn < n) out[gn * 8 + a] = acc;
}

extern "C" void kernel_launch(void* const* d_in, const int* in_sizes, int n_in,
                              void* d_out, int out_size, void* d_ws, size_t ws_size,
                              hipStream_t stream) {
    const float* x   = (const float*)d_in[0];
    const int*   ei  = (const int*)d_in[1];
    const float* W1  = (const float*)d_in[2];
    const float* b1  = (const float*)d_in[3];
    const float* W2  = (const float*)d_in[4];
    const float* b2  = (const float*)d_in[5];
    const float* Wfc = (const float*)d_in[6];
    const float* bfc = (const float*)d_in[7];
    float* out = (float*)d_out;

    const int n = NN, e = EE;
    const int nb = (n + 1023) / 1024;   // 98 scan blocks

    // workspace layout
    char* ws = (char*)d_ws;
    float* dis       = (float*)(ws);                        // N f32
    int*   cnt       = (int*)  (ws + (1 << 19));            // N i32
    int*   row_start = (int*)  (ws + 2 * (1 << 19));        // N i32
    int*   cur       = (int*)  (ws + 3 * (1 << 19));        // N i32
    int*   partial   = (int*)  (ws + 4 * (1 << 19));        // nb i32
    int*   csr_src   = (int*)  (ws + 4 * (1 << 19) + 4096); // E i32 (6.4 MB)
    char*  big       = ws + 4 * (1 << 19) + 4096 + ((size_t)EE * 4 + 4096);
    float* bufA = (float*)(big);                            // N*128 f32 (51.2 MB)
    float* bufB = (float*)(big + (size_t)NN * 128 * 4);

    const int g256n = (n + 255) / 256;
    const int g256e = (e + 255) / 256;

    // ---- CSR build + norms ----
    k_zero_int<<<g256n, 256, 0, stream>>>(cnt, n);
    k_count<<<g256e, 256, 0, stream>>>(ei, cnt, e);
    k_scan_partial<<<nb, 256, 0, stream>>>(cnt, partial, n);
    k_scan_top<<<1, 256, 0, stream>>>(partial, nb);
    k_scan_final<<<nb, 256, 0, stream>>>(cnt, partial, row_start, dis, n);
    k_zero_int<<<g256n, 256, 0, stream>>>(cur, n);
    k_fill<<<g256e, 256, 0, stream>>>(ei, row_start, cur, csr_src, e);

    const int gemm_grid = (n + BM - 1) / BM;
    const int agg_grid  = (n + 3) / 4;

    // ---- layer 1 ----
    k_gemm_scale<<<gemm_grid, 256, 0, stream>>>(x, W1, dis, bufA, n);
    k_agg<<<agg_grid, 256, 0, stream>>>(csr_src, row_start, bufA, dis, b1, bufB, n, e);

    // ---- layer 2 ----
    k_gemm_scale<<<gemm_grid, 256, 0, stream>>>(bufB, W2, dis, bufA, n);
    k_agg<<<agg_grid, 256, 0, stream>>>(csr_src, row_start, bufA, dis, b2, bufB, n, e);

    // ---- FC head ----
    k_fc<<<(n + 31) / 32, 256, 0, stream>>>(bufB, Wfc, bfc, out, n);
}

// Round 4
// 468.761 us; speedup vs baseline: 11.9547x; 1.1499x over previous
//
#include <hip/hip_runtime.h>
#include <hip/hip_bf16.h>

#define NN 100000
#define EE 1600000
#define FF 128
#define HH 128
#define AA 8

typedef unsigned int u32;

__device__ inline u32 packbf2(float a, float b) {
    __hip_bfloat162 t;
    t.x = __float2bfloat16(a);
    t.y = __float2bfloat16(b);
    return *(u32*)&t;
}
__device__ inline float2 unpackbf2(u32 v) {
    union { u32 u; float f; } lo, hi;
    lo.u = v << 16;
    hi.u = v & 0xffff0000u;
    return make_float2(lo.f, hi.f);
}

// ---------------- small utility kernels ----------------
__global__ void k_zero_int(int* p, int n) {
    int i = blockIdx.x * blockDim.x + threadIdx.x;
    if (i < n) p[i] = 0;
}

__global__ void k_count(const int* __restrict__ ei, int* __restrict__ cnt, int e) {
    int i = blockIdx.x * blockDim.x + threadIdx.x;
    if (i < e) atomicAdd(&cnt[ei[e + i]], 1);   // dst rows live at ei[E..2E)
}

// ---------------- 3-phase parallel exclusive scan over cnt[n] ----------------
__global__ __launch_bounds__(256)
void k_scan_partial(const int* __restrict__ cnt, int* __restrict__ partial, int n) {
    __shared__ int s[256];
    const int t = threadIdx.x;
    const int base = blockIdx.x * 1024 + t * 4;
    int sum = 0;
#pragma unroll
    for (int i = 0; i < 4; i++) {
        int idx = base + i;
        if (idx < n) sum += cnt[idx];
    }
    s[t] = sum;
    __syncthreads();
#pragma unroll
    for (int off = 128; off > 0; off >>= 1) {
        if (t < off) s[t] += s[t + off];
        __syncthreads();
    }
    if (t == 0) partial[blockIdx.x] = s[0];
}

__global__ __launch_bounds__(256)
void k_scan_top(int* __restrict__ partial, int nb) {
    __shared__ int s[256];
    const int t = threadIdx.x;
    s[t] = (t < nb) ? partial[t] : 0;
    __syncthreads();
    for (int off = 1; off < 256; off <<= 1) {
        int v = (t >= off) ? s[t - off] : 0;
        __syncthreads();
        s[t] += v;
        __syncthreads();
    }
    if (t < nb) partial[t] = (t == 0) ? 0 : s[t - 1];
}

__global__ __launch_bounds__(256)
void k_scan_final(const int* __restrict__ cnt, const int* __restrict__ partial,
                  int* __restrict__ row_start, float* __restrict__ dis, int n) {
    __shared__ int s[256];
    const int t = threadIdx.x;
    const int base = blockIdx.x * 1024 + t * 4;
    int v[4];
    int sum = 0;
#pragma unroll
    for (int i = 0; i < 4; i++) {
        int idx = base + i;
        v[i] = (idx < n) ? cnt[idx] : 0;
        sum += v[i];
    }
    s[t] = sum;
    __syncthreads();
    for (int off = 1; off < 256; off <<= 1) {
        int x = (t >= off) ? s[t - off] : 0;
        __syncthreads();
        s[t] += x;
        __syncthreads();
    }
    int run = partial[blockIdx.x] + ((t == 0) ? 0 : s[t - 1]);
#pragma unroll
    for (int i = 0; i < 4; i++) {
        int idx = base + i;
        if (idx < n) {
            row_start[idx] = run;
            dis[idx] = rsqrtf((float)v[i] + 1.0f);
            run += v[i];
        }
    }
}

// ---------------- XCD-partitioned bucket fill ----------------
// block b: partition p = b&7 (round-robin XCD), edge chunk c = b>>3.
// Only dsts in partition p are handled by this block, so all writes to the
// p-th slice of csr_src come from one XCD -> lines stay in its L2.
#define FILL_CHUNKS 256
__global__ __launch_bounds__(256)
void k_fill_part(const int* __restrict__ ei, const int* __restrict__ row_start,
                 int* __restrict__ cur, int* __restrict__ csr_src, int e, int n) {
    const int part = blockIdx.x & 7;
    const int psz  = (n + 7) >> 3;
    const int plo  = part * psz;
    const int phi  = min(n, plo + psz);
    const int per  = (e + FILL_CHUNKS - 1) / FILL_CHUNKS;
    const int i0 = (blockIdx.x >> 3) * per;
    const int i1 = min(e, i0 + per);
    for (int i = i0 + threadIdx.x; i < i1; i += 256) {
        int dst = ei[e + i];
        if (dst >= plo && dst < phi) {
            int src = ei[i];
            int pos = row_start[dst] + atomicAdd(&cur[dst], 1);
            csr_src[pos] = src;
        }
    }
}

// ------- GEMM: hwbf[i][j] = bf16( dis[i] * sum_k A[i][k] W[k][j] ) -------
#define BM 64
#define BK 32

__launch_bounds__(256, 2)
__global__ void k_gemm_scale_bf(const float* __restrict__ A,
                                const float* __restrict__ W,
                                const float* __restrict__ dis,
                                u32* __restrict__ outbf,   // rows of 64 u32 (128 bf16)
                                int n)
{
    __shared__ float sA[BK][BM + 4];
    __shared__ float sB[BK][128];
    const int tid = threadIdx.x;
    const int row0 = blockIdx.x * BM;
    const int tr = tid >> 4;
    const int tc = tid & 15;

    float acc[4][8];
#pragma unroll
    for (int r = 0; r < 4; r++)
#pragma unroll
        for (int c = 0; c < 8; c++) acc[r][c] = 0.f;

    for (int k0 = 0; k0 < 128; k0 += BK) {
        __syncthreads();
#pragma unroll
        for (int i = 0; i < 2; i++) {
            int f = tid + i * 256;
            int row = f >> 3;
            int kq = f & 7;
            int gr = row0 + row; if (gr >= n) gr = n - 1;
            float4 v = *(const float4*)&A[(long long)gr * 128 + k0 + kq * 4];
            sA[kq * 4 + 0][row] = v.x;
            sA[kq * 4 + 1][row] = v.y;
            sA[kq * 4 + 2][row] = v.z;
            sA[kq * 4 + 3][row] = v.w;
        }
#pragma unroll
        for (int i = 0; i < 4; i++) {
            int f = tid + i * 256;
            int kk = f >> 5;
            int cq = f & 31;
            *(float4*)&sB[kk][cq * 4] = *(const float4*)&W[(k0 + kk) * 128 + cq * 4];
        }
        __syncthreads();
#pragma unroll
        for (int kk = 0; kk < BK; kk++) {
            float4 a4 = *(const float4*)&sA[kk][tr * 4];
            float4 bl = *(const float4*)&sB[kk][tc * 4];
            float4 bh = *(const float4*)&sB[kk][64 + tc * 4];
            float a_[4] = {a4.x, a4.y, a4.z, a4.w};
            float b_[8] = {bl.x, bl.y, bl.z, bl.w, bh.x, bh.y, bh.z, bh.w};
#pragma unroll
            for (int r = 0; r < 4; r++)
#pragma unroll
                for (int c = 0; c < 8; c++)
                    acc[r][c] += a_[r] * b_[c];
        }
    }
#pragma unroll
    for (int r = 0; r < 4; r++) {
        int gr = row0 + tr * 4 + r;
        if (gr < n) {
            float d = dis[gr];
            uint2 lo, hi;
            lo.x = packbf2(acc[r][0] * d, acc[r][1] * d);
            lo.y = packbf2(acc[r][2] * d, acc[r][3] * d);
            hi.x = packbf2(acc[r][4] * d, acc[r][5] * d);
            hi.y = packbf2(acc[r][6] * d, acc[r][7] * d);
            *(uint2*)&outbf[(long long)gr * 64 + tc * 2]      = lo;
            *(uint2*)&outbf[(long long)gr * 64 + 32 + tc * 2] = hi;
        }
    }
}

// ------- fused gather-aggregate(bf16 table) + self + scale + bias + relu -------
// one 64-lane wave per dst node; lane owns 2 feature columns (1 u32 = 2 bf16)
__launch_bounds__(256)
__global__ void k_agg(const int* __restrict__ csr_src,
                      const int* __restrict__ row_start,
                      const u32* __restrict__ hw,      // bf16x2 rows of 64
                      const float* __restrict__ dis,
                      const float* __restrict__ b,
                      float* __restrict__ out, int n, int e)
{
    int node = blockIdx.x * 4 + (threadIdx.x >> 6);
    if (node >= n) return;
    int lane = threadIdx.x & 63;
    int beg = row_start[node];
    int end = (node == n - 1) ? e : row_start[node + 1];

    float2 acc = unpackbf2(hw[(long long)node * 64 + lane]);  // self-loop term
    int i = beg;
    for (; i + 1 < end; i += 2) {
        int s0 = csr_src[i];
        int s1 = csr_src[i + 1];
        float2 v0 = unpackbf2(hw[(long long)s0 * 64 + lane]);
        float2 v1 = unpackbf2(hw[(long long)s1 * 64 + lane]);
        acc.x += v0.x + v1.x;
        acc.y += v0.y + v1.y;
    }
    if (i < end) {
        float2 v0 = unpackbf2(hw[(long long)csr_src[i] * 64 + lane]);
        acc.x += v0.x;
        acc.y += v0.y;
    }
    float d = dis[node];
    float2 bb = *(const float2*)&b[lane * 2];
    float2 o;
    o.x = fmaxf(fmaf(d, acc.x, bb.x), 0.f);
    o.y = fmaxf(fmaf(d, acc.y, bb.y), 0.f);
    *(float2*)&out[(long long)node * 128 + lane * 2] = o;
}

// ---------------- FC head ----------------
__launch_bounds__(256)
__global__ void k_fc(const float* __restrict__ h,
                     const float* __restrict__ Wfc,
                     const float* __restrict__ bfc,
                     float* __restrict__ out, int n)
{
    __shared__ float sW[128 * 8];
    __shared__ float sH[32][132];
    const int tid = threadIdx.x;
    *(float4*)&sW[tid * 4] = *(const float4*)&Wfc[tid * 4];
    const int n0 = blockIdx.x * 32;
#pragma unroll
    for (int i = 0; i < 4; i++) {
        int f = tid + i * 256;
        int node = f >> 5;
        int kq = f & 31;
        int gn = n0 + node; if (gn >= n) gn = n - 1;
        *(float4*)&sH[node][kq * 4] = *(const float4*)&h[(long long)gn * 128 + kq * 4];
    }
    __syncthreads();
    const int node = tid >> 3;
    const int a = tid & 7;
    float acc = bfc[a];
#pragma unroll
    for (int k = 0; k < 128; k++)
        acc += sH[node][k] * sW[k * 8 + a];
    int gn = n0 + node;
    if (gn < n) out[gn * 8 + a] = acc;
}

extern "C" void kernel_launch(void* const* d_in, const int* in_sizes, int n_in,
                              void* d_out, int out_size, void* d_ws, size_t ws_size,
                              hipStream_t stream) {
    const float* x   = (const float*)d_in[0];
    const int*   ei  = (const int*)d_in[1];
    const float* W1  = (const float*)d_in[2];
    const float* b1  = (const float*)d_in[3];
    const float* W2  = (const float*)d_in[4];
    const float* b2  = (const float*)d_in[5];
    const float* Wfc = (const float*)d_in[6];
    const float* bfc = (const float*)d_in[7];
    float* out = (float*)d_out;

    const int n = NN, e = EE;
    const int nb = (n + 1023) / 1024;

    // workspace layout
    char* ws = (char*)d_ws;
    float* dis       = (float*)(ws);                        // N f32
    int*   cnt       = (int*)  (ws + (1 << 19));            // N i32
    int*   row_start = (int*)  (ws + 2 * (1 << 19));        // N i32
    int*   cur       = (int*)  (ws + 3 * (1 << 19));        // N i32
    int*   partial   = (int*)  (ws + 4 * (1 << 19));        // nb i32
    int*   csr_src   = (int*)  (ws + 4 * (1 << 19) + 4096); // E i32 (6.4 MB)
    char*  big       = ws + 4 * (1 << 19) + 4096 + ((size_t)EE * 4 + 4096);
    u32*   hwbf      = (u32*)(big);                          // N*64 u32 (25.6 MB)
    float* bufH      = (float*)(big + (size_t)NN * 64 * 4);  // N*128 f32 (51.2 MB)

    const int g256n = (n + 255) / 256;
    const int g256e = (e + 255) / 256;

    // ---- CSR build + norms ----
    k_zero_int<<<g256n, 256, 0, stream>>>(cnt, n);
    k_count<<<g256e, 256, 0, stream>>>(ei, cnt, e);
    k_scan_partial<<<nb, 256, 0, stream>>>(cnt, partial, n);
    k_scan_top<<<1, 256, 0, stream>>>(partial, nb);
    k_scan_final<<<nb, 256, 0, stream>>>(cnt, partial, row_start, dis, n);
    k_zero_int<<<g256n, 256, 0, stream>>>(cur, n);
    k_fill_part<<<FILL_CHUNKS * 8, 256, 0, stream>>>(ei, row_start, cur, csr_src, e, n);

    const int gemm_grid = (n + BM - 1) / BM;
    const int agg_grid  = (n + 3) / 4;

    // ---- layer 1 ----
    k_gemm_scale_bf<<<gemm_grid, 256, 0, stream>>>(x, W1, dis, hwbf, n);
    k_agg<<<agg_grid, 256, 0, stream>>>(csr_src, row_start, hwbf, dis, b1, bufH, n, e);

    // ---- layer 2 ----
    k_gemm_scale_bf<<<gemm_grid, 256, 0, stream>>>(bufH, W2, dis, hwbf, n);
    k_agg<<<agg_grid, 256, 0, stream>>>(csr_src, row_start, hwbf, dis, b2, bufH, n, e);

    // ---- FC head ----
    k_fc<<<(n + 31) / 32, 256, 0, stream>>>(bufH, Wfc, bfc, out, n);
}